// Round 11
// baseline (1102.436 us; speedup 1.0000x reference)
//
#include <hip/hip_runtime.h>
#include <hip/hip_bf16.h>

#define N_TOK 8192
#define H_DIM 1024
#define I_DIM 3584
#define N_EXP 8
#define N_PAIR (N_TOK * 2)

#define BM 256
#define BN 128
#define BK 32
#define MAX_TILES 72   // worst case sum ceil(c_e/256) = 64 + 8 = 72

#define NPAN1 (I_DIM / BN)             // 28
#define NPAN2 (H_DIM / BN)             // 8
#define NWG1  (MAX_TILES * NPAN1)      // 2016 (div by 8)
#define NWG2  (MAX_TILES * NPAN2)      // 576 (div by 8); no split-K

typedef short bf16x8 __attribute__((ext_vector_type(8)));
typedef float f32x4 __attribute__((ext_vector_type(4)));

#define CFENCE() asm volatile("" ::: "memory")

#define MFMA_BF16 __builtin_amdgcn_mfma_f32_16x16x32_bf16

// ---------------- ws layout (bytes) ----------------
#define WS_CNT      0
#define WS_FILL     64
#define WS_OFF      128
#define WS_NTILES   192
#define WS_TILETAB  256
#define WS_SEL      2048
#define WS_WGT      (WS_SEL    + 2 * N_TOK * 4)
#define WS_PTOK     (WS_WGT    + 2 * N_TOK * 4)
#define WS_PW       (WS_PTOK   + N_PAIR * 4)
#define WS_XBF      (WS_PW     + N_PAIR * 4)
#define WS_HBUF     (WS_XBF    + (size_t)N_TOK * H_DIM * 2)
#define WBF_ELEMS   ((size_t)N_EXP * I_DIM * H_DIM)
#define WS_WGBF     (WS_HBUF + (size_t)N_PAIR * I_DIM * 2)
#define WS_WUBF     (WS_WGBF + WBF_ELEMS * 2)
#define WS_END      (WS_WUBF + WBF_ELEMS * 2)                  // ~252 MB
#define WS_TOKROW   WS_END                                     // 2*N_TOK ints
#define WS_OBUF     (WS_TOKROW + (size_t)2 * N_TOK * 4)
#define WS_END2     (WS_OBUF + (size_t)N_PAIR * H_DIM * 4)     // +67 MB

__device__ __forceinline__ unsigned short f2bf(float f) {
  unsigned int u = __float_as_uint(f);
  unsigned int r = (u + 0x7fffu + ((u >> 16) & 1u)) >> 16;
  return (unsigned short)r;
}

__device__ __forceinline__ uint4 pack8(float4 a, float4 b) {
  uint4 r;
  r.x = (unsigned)f2bf(a.x) | ((unsigned)f2bf(a.y) << 16);
  r.y = (unsigned)f2bf(a.z) | ((unsigned)f2bf(a.w) << 16);
  r.z = (unsigned)f2bf(b.x) | ((unsigned)f2bf(b.y) << 16);
  r.w = (unsigned)f2bf(b.z) | ((unsigned)f2bf(b.w) << 16);
  return r;
}

__device__ __forceinline__ void gll16(const ushort* g, ushort* l) {
  __builtin_amdgcn_global_load_lds(
      (const __attribute__((address_space(1))) unsigned int*)g,
      (__attribute__((address_space(3))) unsigned int*)l, 16, 0, 0);
}

// ---------------- router ----------------
__global__ __launch_bounds__(64) void k_router(
    const float* __restrict__ x, const float* __restrict__ gw,
    float* __restrict__ logits, int* __restrict__ sel,
    float* __restrict__ wgt, int* __restrict__ cnt,
    ushort* __restrict__ xbf)
{
  const int n = blockIdx.x;
  const int lane = threadIdx.x;
  const float4* xr = (const float4*)(x + (size_t)n * H_DIM + lane * 16);
  float4 x0 = xr[0], x1 = xr[1], x2 = xr[2], x3 = xr[3];

  uint4* xo = (uint4*)(xbf + (size_t)n * H_DIM + lane * 16);
  xo[0] = pack8(x0, x1);
  xo[1] = pack8(x2, x3);

  float l[N_EXP];
#pragma unroll
  for (int e = 0; e < N_EXP; ++e) {
    const float4* wr = (const float4*)(gw + e * H_DIM + lane * 16);
    float4 w0 = wr[0], w1 = wr[1], w2 = wr[2], w3 = wr[3];
    float p = x0.x * w0.x + x0.y * w0.y + x0.z * w0.z + x0.w * w0.w
            + x1.x * w1.x + x1.y * w1.y + x1.z * w1.z + x1.w * w1.w
            + x2.x * w2.x + x2.y * w2.y + x2.z * w2.z + x2.w * w2.w
            + x3.x * w3.x + x3.y * w3.y + x3.z * w3.z + x3.w * w3.w;
#pragma unroll
    for (int o = 32; o >= 1; o >>= 1) p += __shfl_xor(p, o, 64);
    l[e] = p;
  }
  float m = l[0];
#pragma unroll
  for (int e = 1; e < N_EXP; ++e) m = fmaxf(m, l[e]);
  float pr[N_EXP]; float den = 0.f;
#pragma unroll
  for (int e = 0; e < N_EXP; ++e) { pr[e] = expf(l[e] - m); den += pr[e]; }
#pragma unroll
  for (int e = 0; e < N_EXP; ++e) pr[e] /= den;
  int i0 = 0; float p0 = pr[0];
#pragma unroll
  for (int e = 1; e < N_EXP; ++e) { if (pr[e] > p0) { p0 = pr[e]; i0 = e; } }
  int i1 = -1; float p1 = -1.f;
#pragma unroll
  for (int e = 0; e < N_EXP; ++e) { if (e != i0 && pr[e] > p1) { p1 = pr[e]; i1 = e; } }
  float rs = 1.f / (p0 + p1);
  if (lane == 0) {
    float* lo = logits + (size_t)n * N_EXP;
#pragma unroll
    for (int e = 0; e < N_EXP; ++e) lo[e] = l[e];
    sel[2 * n] = i0; sel[2 * n + 1] = i1;
    wgt[2 * n] = p0 * rs; wgt[2 * n + 1] = p1 * rs;
    atomicAdd(&cnt[i0], 1);
    atomicAdd(&cnt[i1], 1);
  }
}

// ---------------- prefix sum + tile table ----------------
__global__ void k_prefix(const int* __restrict__ cnt, int* __restrict__ off,
                         int* __restrict__ ntiles, int* __restrict__ tab)
{
  if (threadIdx.x != 0 || blockIdx.x != 0) return;
  int acc = 0, nt = 0;
  for (int e = 0; e < N_EXP; ++e) {
    off[e] = acc;
    int c = cnt[e];
    for (int r = 0; r < c; r += BM) {
      tab[nt * 3 + 0] = e;
      tab[nt * 3 + 1] = acc + r;
      tab[nt * 3 + 2] = (c - r < BM) ? (c - r) : BM;
      nt++;
    }
    acc += c;
  }
  off[N_EXP] = acc;
  *ntiles = nt;
}

// ---------------- scatter (+ token -> pair-row index) ----------------
__global__ __launch_bounds__(256) void k_scatter(
    const int* __restrict__ sel, const float* __restrict__ wgt,
    const int* __restrict__ off, int* __restrict__ fill,
    int* __restrict__ ptok, float* __restrict__ pw,
    int* __restrict__ tokrow)
{
  int n = blockIdx.x * 256 + threadIdx.x;
  if (n >= N_TOK) return;
#pragma unroll
  for (int k = 0; k < 2; ++k) {
    int e = sel[2 * n + k];
    int pos = atomicAdd(&fill[e], 1);
    int row = off[e] + pos;
    ptok[row] = n;
    pw[row] = wgt[2 * n + k];
    if (tokrow) tokrow[2 * n + k] = row;
  }
}

// ---------------- fp32 -> bf16 weight conversion ----------------
__global__ __launch_bounds__(256) void k_cvtw(const float* __restrict__ src,
                                              ushort* __restrict__ dst)
{
  size_t i = (size_t)blockIdx.x * 256 + threadIdx.x;
  const float4* s = (const float4*)(src + i * 8);
  float4 a = s[0], b = s[1];
  ((uint4*)dst)[i] = pack8(a, b);
}

// ---------------- final reduce: out[n] = obuf[r0] + obuf[r1] ----------------
__global__ __launch_bounds__(256) void k_reduce(
    const float* __restrict__ obuf, const int* __restrict__ tokrow,
    float* __restrict__ out)
{
  const int n = blockIdx.x;
  const int t = threadIdx.x;            // 256 threads x float4 = 1024 floats
  const int r0 = tokrow[2 * n];
  const int r1 = tokrow[2 * n + 1];
  const float4* p0 = (const float4*)(obuf + (size_t)r0 * H_DIM);
  const float4* p1 = (const float4*)(obuf + (size_t)r1 * H_DIM);
  float4 a = p0[t], b = p1[t];
  float4 v = make_float4(a.x + b.x, a.y + b.y, a.z + b.z, a.w + b.w);
  ((float4*)(out + (size_t)n * H_DIM))[t] = v;
}

// ================= FAST PATH: 3-buffer deep pipeline, distributed stages ======
// Per step k: entry {vmcnt(N); s_barrier; fence} ensures stage(k) landed.
// 4 phases: {ds_read quarter; setprio(1) MFMA setprio(0); 1 stage-issue of
// stage(k+2) into buf[(k+2)%3] (!= read buf); CFENCE}. Trailing
// {lgkmcnt(0); s_barrier; fence} lets step k+1's stage overwrite buf[(k+3)%3].
// vmcnt FIFO: exactly N loads issued per step, in order -> vmcnt(N) at entry
// retires the current read-buffer's loads. Prologue issues stage(0), stage(1).

// pass A: h = silu(x@Wg^T) * (x@Wu^T)
__global__ __launch_bounds__(512) void k_mlp1b(
    const ushort* __restrict__ Wg, const ushort* __restrict__ Wu,
    const ushort* __restrict__ xbf, const int* __restrict__ ptok,
    const int* __restrict__ ntiles, const int* __restrict__ tab,
    ushort* __restrict__ hbuf)
{
  __shared__ ushort sA[3][BM * BK];   // 3 x 16 KB
  __shared__ ushort sG[3][BN * BK];   // 3 x 8 KB
  __shared__ ushort sU[3][BN * BK];   // 3 x 8 KB
  __shared__ int stok[BM];

  const int orig = blockIdx.x;
  const int lin = (orig & 7) * (NWG1 >> 3) + (orig >> 3);
  const int tile = lin / NPAN1;
  const int i0 = (lin % NPAN1) * BN;

  if (tile >= *ntiles) return;
  const int e = tab[tile * 3 + 0];
  const int row0 = tab[tile * 3 + 1];
  const int nrows = tab[tile * 3 + 2];
  const int t = threadIdx.x;

  if (t < BM) {
    int tt = t < nrows ? t : (nrows - 1);
    stok[t] = ptok[row0 + tt];
  }
  __syncthreads();   // drains all prior VMEM -> clean vmcnt baseline

  // T2 pre-swizzled source chunk (rule #21 both-sides; R10-verified: conflicts=0)
  const int ak = (((t & 3) ^ ((t >> 3) & 3)) * 8);
  const int ar = t >> 2;
  const ushort* ga0 = xbf + (size_t)stok[ar] * H_DIM + ak;
  const ushort* ga1 = xbf + (size_t)stok[128 + ar] * H_DIM + ak;
  const ushort* gg0 = Wg + (size_t)e * I_DIM * H_DIM + (size_t)(i0 + ar) * H_DIM + ak;
  const ushort* gu0 = Wu + (size_t)e * I_DIM * H_DIM + (size_t)(i0 + ar) * H_DIM + ak;

  const int lane = t & 63, wid = t >> 6;
  const int wm = wid >> 1, wn = wid & 1;   // 4 x 2 wave grid
  const int fr = lane & 15, fq = lane >> 4;
  const int fs = (fq ^ ((fr >> 1) & 3)) * 8;

  f32x4 ag[4][4], au[4][4];
#pragma unroll
  for (int m = 0; m < 4; ++m)
#pragma unroll
    for (int n = 0; n < 4; ++n) { ag[m][n] = (f32x4){0,0,0,0}; au[m][n] = (f32x4){0,0,0,0}; }

#define STAGE1(b, kt) do {                      \
    gll16(ga0 + (kt), &sA[b][t * 8]);           \
    gll16(ga1 + (kt), &sA[b][(512 + t) * 8]);   \
    gll16(gg0 + (kt), &sG[b][t * 8]);           \
    gll16(gu0 + (kt), &sU[b][t * 8]);           \
  } while (0)

  // 4 phases; stage issues distributed one-per-phase (order pinned by CFENCE)
#define STEP1(rb, wb, KT, DOSTAGE) do {                                       \
    bf16x8 a_[4];                                                             \
    _Pragma("unroll")                                                         \
    for (int m = 0; m < 4; ++m)                                               \
      a_[m] = *(const bf16x8*)(&sA[rb][(wm * 64 + m * 16 + fr) * BK + fs]);   \
    _Pragma("unroll")                                                         \
    for (int n = 0; n < 4; ++n) {                                             \
      bf16x8 bg_ = *(const bf16x8*)(&sG[rb][(wn * 64 + n * 16 + fr) * BK + fs]); \
      bf16x8 bu_ = *(const bf16x8*)(&sU[rb][(wn * 64 + n * 16 + fr) * BK + fs]); \
      __builtin_amdgcn_s_setprio(1);                                          \
      _Pragma("unroll")                                                       \
      for (int m = 0; m < 4; ++m) {                                           \
        ag[m][n] = MFMA_BF16(a_[m], bg_, ag[m][n], 0, 0, 0);                  \
        au[m][n] = MFMA_BF16(a_[m], bu_, au[m][n], 0, 0, 0);                  \
      }                                                                       \
      __builtin_amdgcn_s_setprio(0);                                          \
      if (DOSTAGE) {                                                          \
        if (n == 0) gll16(ga0 + (KT), &sA[wb][t * 8]);                        \
        if (n == 1) gll16(ga1 + (KT), &sA[wb][(512 + t) * 8]);                \
        if (n == 2) gll16(gg0 + (KT), &sG[wb][t * 8]);                        \
        if (n == 3) gll16(gu0 + (KT), &sU[wb][t * 8]);                        \
      }                                                                       \
      CFENCE();                                                               \
    }                                                                         \
  } while (0)

  const int NK = H_DIM / BK;  // 32
  STAGE1(0, 0);
  CFENCE();                   // pin FIFO: buf0's 4 loads oldest
  STAGE1(1, BK);
  CFENCE();

  int rb = 0;
  for (int ki = 0; ki <= NK - 3; ++ki) {     // steps that still stage
    asm volatile("s_waitcnt vmcnt(4)" ::: "memory");
    __builtin_amdgcn_s_barrier();
    CFENCE();
    __builtin_amdgcn_sched_barrier(0);
    const int wb = (rb + 2 >= 3) ? rb - 1 : rb + 2;
    STEP1(rb, wb, (ki + 2) * BK, 1);
    asm volatile("s_waitcnt lgkmcnt(0)" ::: "memory");
    __builtin_amdgcn_sched_barrier(0);
    __builtin_amdgcn_s_barrier();
    CFENCE();
    rb = (rb + 1 >= 3) ? 0 : rb + 1;
  }
  // step NK-2 (no stage)
  asm volatile("s_waitcnt vmcnt(4)" ::: "memory");
  __builtin_amdgcn_s_barrier();
  CFENCE();
  __builtin_amdgcn_sched_barrier(0);
  STEP1(rb, 0, 0, 0);
  rb = (rb + 1 >= 3) ? 0 : rb + 1;
  // step NK-1 (last)
  asm volatile("s_waitcnt vmcnt(0)" ::: "memory");
  __builtin_amdgcn_s_barrier();
  CFENCE();
  __builtin_amdgcn_sched_barrier(0);
  STEP1(rb, 0, 0, 0);
#undef STEP1
#undef STAGE1

#pragma unroll
  for (int m = 0; m < 4; ++m) {
    const int rbv = wm * 64 + m * 16 + fq * 4;
#pragma unroll
    for (int n = 0; n < 4; ++n) {
      const int col = i0 + wn * 64 + n * 16 + fr;
#pragma unroll
      for (int r = 0; r < 4; ++r) {
        const int row = rbv + r;
        if (row < nrows) {
          float g = ag[m][n][r], u = au[m][n][r];
          float hv = (g / (1.f + __expf(-g))) * u;
          hbuf[(size_t)(row0 + row) * I_DIM + col] = f2bf(hv);
        }
      }
    }
  }
}

// pass B: partial = w * (h @ Wd^T); EPI=0 -> plain store to obuf; EPI=1 -> atomicAdd out
template <int EPI>
__global__ __launch_bounds__(512) void k_mlp2b(
    const ushort* __restrict__ Wd, const ushort* __restrict__ hbuf,
    const int* __restrict__ ptok, const float* __restrict__ pw,
    const int* __restrict__ ntiles, const int* __restrict__ tab,
    float* __restrict__ dst)
{
  __shared__ ushort sA[3][BM * BK];   // 3 x 16 KB
  __shared__ ushort sB[3][BN * BK];   // 3 x 8 KB
  __shared__ int stok[BM];
  __shared__ float sw[BM];

  const int orig = blockIdx.x;
  const int lin = (orig & 7) * (NWG2 >> 3) + (orig >> 3);
  const int tile = lin / NPAN2;
  const int j0 = (lin % NPAN2) * BN;

  if (tile >= *ntiles) return;
  const int e = tab[tile * 3 + 0];
  const int row0 = tab[tile * 3 + 1];
  const int nrows = tab[tile * 3 + 2];
  const int t = threadIdx.x;

  if (t < BM) {
    int tt = t < nrows ? t : (nrows - 1);
    stok[t] = ptok[row0 + tt];
    sw[t] = pw[row0 + tt];
  }
  __syncthreads();

  const int ak = (((t & 3) ^ ((t >> 3) & 3)) * 8);
  const int ar = t >> 2;
  int arow0 = row0 + ar;        if (arow0 > N_PAIR - 1) arow0 = N_PAIR - 1;
  int arow1 = row0 + 128 + ar;  if (arow1 > N_PAIR - 1) arow1 = N_PAIR - 1;
  const ushort* ga0 = hbuf + (size_t)arow0 * I_DIM + ak;
  const ushort* ga1 = hbuf + (size_t)arow1 * I_DIM + ak;
  const ushort* gb0 = Wd + (size_t)e * H_DIM * I_DIM + (size_t)(j0 + ar) * I_DIM + ak;

  const int lane = t & 63, wid = t >> 6;
  const int wm = wid >> 1, wn = wid & 1;
  const int fr = lane & 15, fq = lane >> 4;
  const int fs = (fq ^ ((fr >> 1) & 3)) * 8;

  f32x4 ac[4][4];
#pragma unroll
  for (int m = 0; m < 4; ++m)
#pragma unroll
    for (int n = 0; n < 4; ++n) ac[m][n] = (f32x4){0,0,0,0};

#define STAGE2(b, kt) do {                      \
    gll16(ga0 + (kt), &sA[b][t * 8]);           \
    gll16(ga1 + (kt), &sA[b][(512 + t) * 8]);   \
    gll16(gb0 + (kt), &sB[b][t * 8]);           \
  } while (0)

#define STEP2(rb, wb, KT, DOSTAGE) do {                                       \
    bf16x8 a_[4];                                                             \
    _Pragma("unroll")                                                         \
    for (int m = 0; m < 4; ++m)                                               \
      a_[m] = *(const bf16x8*)(&sA[rb][(wm * 64 + m * 16 + fr) * BK + fs]);   \
    _Pragma("unroll")                                                         \
    for (int n = 0; n < 4; ++n) {                                             \
      bf16x8 bb_ = *(const bf16x8*)(&sB[rb][(wn * 64 + n * 16 + fr) * BK + fs]); \
      __builtin_amdgcn_s_setprio(1);                                          \
      _Pragma("unroll")                                                       \
      for (int m = 0; m < 4; ++m)                                             \
        ac[m][n] = MFMA_BF16(a_[m], bb_, ac[m][n], 0, 0, 0);                  \
      __builtin_amdgcn_s_setprio(0);                                          \
      if (DOSTAGE) {                                                          \
        if (n == 0) gll16(ga0 + (KT), &sA[wb][t * 8]);                        \
        if (n == 1) gll16(ga1 + (KT), &sA[wb][(512 + t) * 8]);                \
        if (n == 2) gll16(gb0 + (KT), &sB[wb][t * 8]);                        \
      }                                                                       \
      CFENCE();                                                               \
    }                                                                         \
  } while (0)

  const int NK = I_DIM / BK;  // 112
  STAGE2(0, 0);
  CFENCE();
  STAGE2(1, BK);
  CFENCE();

  int rb = 0;
  for (int ki = 0; ki <= NK - 3; ++ki) {
    asm volatile("s_waitcnt vmcnt(3)" ::: "memory");
    __builtin_amdgcn_s_barrier();
    CFENCE();
    __builtin_amdgcn_sched_barrier(0);
    const int wb = (rb + 2 >= 3) ? rb - 1 : rb + 2;
    STEP2(rb, wb, (ki + 2) * BK, 1);
    asm volatile("s_waitcnt lgkmcnt(0)" ::: "memory");
    __builtin_amdgcn_sched_barrier(0);
    __builtin_amdgcn_s_barrier();
    CFENCE();
    rb = (rb + 1 >= 3) ? 0 : rb + 1;
  }
  asm volatile("s_waitcnt vmcnt(3)" ::: "memory");
  __builtin_amdgcn_s_barrier();
  CFENCE();
  __builtin_amdgcn_sched_barrier(0);
  STEP2(rb, 0, 0, 0);
  rb = (rb + 1 >= 3) ? 0 : rb + 1;
  asm volatile("s_waitcnt vmcnt(0)" ::: "memory");
  __builtin_amdgcn_s_barrier();
  CFENCE();
  __builtin_amdgcn_sched_barrier(0);
  STEP2(rb, 0, 0, 0);
#undef STEP2
#undef STAGE2

#pragma unroll
  for (int m = 0; m < 4; ++m) {
    const int rbv = wm * 64 + m * 16 + fq * 4;
#pragma unroll
    for (int n = 0; n < 4; ++n) {
      const int col = j0 + wn * 64 + n * 16 + fr;
#pragma unroll
      for (int r = 0; r < 4; ++r) {
        const int row = rbv + r;
        if (row < nrows) {
          float v = ac[m][n][r] * sw[row];
          if (EPI == 0) {
            dst[(size_t)(row0 + row) * H_DIM + col] = v;          // obuf, no atomics
          } else {
            atomicAdd(&dst[(size_t)stok[row] * H_DIM + col], v);  // out
          }
        }
      }
    }
  }
}

// ================= FALLBACK PATH (fp32 weights, reg-staged, 128-tile) =====

#define FBM 128
#define FBN 128

__global__ __launch_bounds__(256) void k_mlp1(
    const float* __restrict__ Wg, const float* __restrict__ Wu,
    const ushort* __restrict__ xbf, const int* __restrict__ ptok,
    const int* __restrict__ ntiles, const int* __restrict__ tab,
    ushort* __restrict__ hbuf)
{
  __shared__ ushort sA[FBM * BK];
  __shared__ ushort sG[FBN * BK];
  __shared__ ushort sU[FBN * BK];
  __shared__ int stok[FBM];

  const int tile = blockIdx.x;
  if (tile >= *ntiles) return;
  const int e = tab[tile * 3 + 0];
  const int row0 = tab[tile * 3 + 1] + (blockIdx.z ? FBM : 0);
  int nrows = tab[tile * 3 + 2] - (blockIdx.z ? FBM : 0);
  if (nrows <= 0) return;
  if (nrows > FBM) nrows = FBM;
  const int i0 = blockIdx.y * FBN;
  const int t = threadIdx.x;

  if (t < FBM) {
    int tt = t < nrows ? t : (nrows - 1);
    stok[t] = ptok[row0 + tt];
  }
  __syncthreads();

  const int ak = (t & 3) * 8;
  const ushort* ga0 = xbf + (size_t)stok[t >> 2] * H_DIM + ak;
  const ushort* ga1 = xbf + (size_t)stok[64 + (t >> 2)] * H_DIM + ak;
  ushort* la0 = sA + (size_t)t * 8;
  ushort* la1 = sA + (size_t)(256 + t) * 8;

  const int wr = t >> 1, wcb = (t & 1) * 16;
  const float* gwg = Wg + (size_t)e * I_DIM * H_DIM + (size_t)(i0 + wr) * H_DIM + wcb;
  const float* gwu = Wu + (size_t)e * I_DIM * H_DIM + (size_t)(i0 + wr) * H_DIM + wcb;
  ushort* lwg = sG + wr * BK + wcb;
  ushort* lwu = sU + wr * BK + wcb;

  const int lane = t & 63, wid = t >> 6;
  const int wm = wid >> 1, wn = wid & 1;
  const int fr = lane & 15, fq = lane >> 4;

  f32x4 ag[4][4], au[4][4];
#pragma unroll
  for (int m = 0; m < 4; ++m)
#pragma unroll
    for (int n = 0; n < 4; ++n) { ag[m][n] = (f32x4){0,0,0,0}; au[m][n] = (f32x4){0,0,0,0}; }

  for (int kt = 0; kt < H_DIM; kt += BK) {
    gll16(ga0 + kt, la0);
    gll16(ga1 + kt, la1);

    const float4* pg = (const float4*)(gwg + kt);
    const float4* pu = (const float4*)(gwu + kt);
    float4 g0 = pg[0], g1 = pg[1], g2 = pg[2], g3 = pg[3];
    float4 u0 = pu[0], u1 = pu[1], u2 = pu[2], u3 = pu[3];
    ((uint4*)lwg)[0] = pack8(g0, g1);
    ((uint4*)lwg)[1] = pack8(g2, g3);
    ((uint4*)lwu)[0] = pack8(u0, u1);
    ((uint4*)lwu)[1] = pack8(u2, u3);
    __syncthreads();

    bf16x8 a[4], bg[4], bu[4];
#pragma unroll
    for (int m = 0; m < 4; ++m)
      a[m] = *(const bf16x8*)(sA + (wm * 64 + m * 16 + fr) * BK + fq * 8);
#pragma unroll
    for (int n = 0; n < 4; ++n) {
      bg[n] = *(const bf16x8*)(sG + (wn * 64 + n * 16 + fr) * BK + fq * 8);
      bu[n] = *(const bf16x8*)(sU + (wn * 64 + n * 16 + fr) * BK + fq * 8);
    }
#pragma unroll
    for (int m = 0; m < 4; ++m)
#pragma unroll
      for (int n = 0; n < 4; ++n) {
        ag[m][n] = MFMA_BF16(a[m], bg[n], ag[m][n], 0, 0, 0);
        au[m][n] = MFMA_BF16(a[m], bu[n], au[m][n], 0, 0, 0);
      }
    __syncthreads();
  }

#pragma unroll
  for (int m = 0; m < 4; ++m) {
    const int rb = wm * 64 + m * 16 + fq * 4;
#pragma unroll
    for (int n = 0; n < 4; ++n) {
      const int col = i0 + wn * 64 + n * 16 + fr;
#pragma unroll
      for (int r = 0; r < 4; ++r) {
        const int row = rb + r;
        if (row < nrows) {
          float g = ag[m][n][r], u = au[m][n][r];
          float hv = (g / (1.f + __expf(-g))) * u;
          hbuf[(size_t)(row0 + row) * I_DIM + col] = f2bf(hv);
        }
      }
    }
  }
}

__global__ __launch_bounds__(256) void k_mlp2(
    const float* __restrict__ Wd, const ushort* __restrict__ hbuf,
    const int* __restrict__ ptok, const float* __restrict__ pw,
    const int* __restrict__ ntiles, const int* __restrict__ tab,
    float* __restrict__ out)
{
  __shared__ ushort sA[FBM * BK];
  __shared__ ushort sB[FBN * BK];
  __shared__ int stok[FBM];
  __shared__ float sw[FBM];

  const int tile = blockIdx.x;
  if (tile >= *ntiles) return;
  const int e = tab[tile * 3 + 0];
  const int row0 = tab[tile * 3 + 1] + (blockIdx.z ? FBM : 0);
  int nrows = tab[tile * 3 + 2] - (blockIdx.z ? FBM : 0);
  if (nrows <= 0) return;
  if (nrows > FBM) nrows = FBM;
  const int j0 = blockIdx.y * FBN;
  const int t = threadIdx.x;

  if (t < FBM) {
    int tt = t < nrows ? t : (nrows - 1);
    stok[t] = ptok[row0 + tt];
    sw[t] = pw[row0 + tt];
  }
  __syncthreads();

  const int ak = (t & 3) * 8;
  int arow0 = row0 + (t >> 2);       if (arow0 > N_PAIR - 1) arow0 = N_PAIR - 1;
  int arow1 = row0 + 64 + (t >> 2);  if (arow1 > N_PAIR - 1) arow1 = N_PAIR - 1;
  const ushort* ga0 = hbuf + (size_t)arow0 * I_DIM + ak;
  const ushort* ga1 = hbuf + (size_t)arow1 * I_DIM + ak;
  ushort* la0 = sA + (size_t)t * 8;
  ushort* la1 = sA + (size_t)(256 + t) * 8;

  const int wr = t >> 1, wcb = (t & 1) * 16;
  const float* gb = Wd + (size_t)e * H_DIM * I_DIM + (size_t)(j0 + wr) * I_DIM + wcb;
  ushort* lb = sB + wr * BK + wcb;

  const int lane = t & 63, wid = t >> 6;
  const int wm = wid >> 1, wn = wid & 1;
  const int fr = lane & 15, fq = lane >> 4;

  f32x4 ac[4][4];
#pragma unroll
  for (int m = 0; m < 4; ++m)
#pragma unroll
    for (int n = 0; n < 4; ++n) ac[m][n] = (f32x4){0,0,0,0};

  for (int kt = 0; kt < I_DIM; kt += BK) {
    gll16(ga0 + kt, la0);
    gll16(ga1 + kt, la1);

    const float4* pb = (const float4*)(gb + kt);
    float4 b0 = pb[0], b1 = pb[1], b2 = pb[2], b3 = pb[3];
    ((uint4*)lb)[0] = pack8(b0, b1);
    ((uint4*)lb)[1] = pack8(b2, b3);
    __syncthreads();

    bf16x8 a[4], bb[4];
#pragma unroll
    for (int m = 0; m < 4; ++m)
      a[m] = *(const bf16x8*)(sA + (wm * 64 + m * 16 + fr) * BK + fq * 8);
#pragma unroll
    for (int n = 0; n < 4; ++n)
      bb[n] = *(const bf16x8*)(sB + (wn * 64 + n * 16 + fr) * BK + fq * 8);
#pragma unroll
    for (int m = 0; m < 4; ++m)
#pragma unroll
      for (int n = 0; n < 4; ++n)
        ac[m][n] = MFMA_BF16(a[m], bb[n], ac[m][n], 0, 0, 0);
    __syncthreads();
  }

#pragma unroll
  for (int m = 0; m < 4; ++m) {
    const int rb = wm * 64 + m * 16 + fq * 4;
#pragma unroll
    for (int n = 0; n < 4; ++n) {
      const int col = j0 + wn * 64 + n * 16 + fr;
#pragma unroll
      for (int r = 0; r < 4; ++r) {
        const int row = rb + r;
        if (row < nrows) {
          float v = ac[m][n][r] * sw[row];
          atomicAdd(&out[(size_t)stok[row] * H_DIM + col], v);
        }
      }
    }
  }
}

// ---------------- host ----------------
extern "C" void kernel_launch(void* const* d_in, const int* in_sizes, int n_in,
                              void* d_out, int out_size, void* d_ws, size_t ws_size,
                              hipStream_t stream)
{
  const float* x  = (const float*)d_in[0];
  const float* gw = (const float*)d_in[1];
  const float* Wg = (const float*)d_in[2];
  const float* Wu = (const float*)d_in[3];
  const float* Wd = (const float*)d_in[4];

  float* out    = (float*)d_out;
  float* logits = out + (size_t)N_TOK * H_DIM;

  char* ws = (char*)d_ws;
  int*    cnt    = (int*)(ws + WS_CNT);
  int*    fill   = (int*)(ws + WS_FILL);
  int*    off    = (int*)(ws + WS_OFF);
  int*    ntiles = (int*)(ws + WS_NTILES);
  int*    tab    = (int*)(ws + WS_TILETAB);
  int*    sel    = (int*)(ws + WS_SEL);
  float*  wgt    = (float*)(ws + WS_WGT);
  int*    ptok   = (int*)(ws + WS_PTOK);
  float*  pw     = (float*)(ws + WS_PW);
  ushort* xbf    = (ushort*)(ws + WS_XBF);
  ushort* hbuf   = (ushort*)(ws + WS_HBUF);
  ushort* wgbf   = (ushort*)(ws + WS_WGBF);
  ushort* wubf   = (ushort*)(ws + WS_WUBF);
  ushort* wdbf   = wgbf;  // aliases Wg slot (disjoint live ranges)
  int*    tokrow = (int*)(ws + WS_TOKROW);
  float*  obuf   = (float*)(ws + WS_OBUF);

  const bool fast  = (ws_size >= WS_END);
  const bool fast2 = (ws_size >= WS_END2);   // room for obuf + tokrow

  if (!fast2) hipMemsetAsync(d_out, 0, (size_t)N_TOK * H_DIM * sizeof(float), stream);
  hipMemsetAsync(ws, 0, 128, stream);  // cnt + fill

  k_router<<<N_TOK, 64, 0, stream>>>(x, gw, logits, sel, wgt, cnt, xbf);
  k_prefix<<<1, 64, 0, stream>>>(cnt, off, ntiles, tab);
  k_scatter<<<N_TOK / 256, 256, 0, stream>>>(sel, wgt, off, fill, ptok, pw,
                                             fast2 ? tokrow : (int*)nullptr);

  const int cvtblocks = (int)(WBF_ELEMS / 8 / 256);  // 14336

  if (fast) {
    k_cvtw<<<cvtblocks, 256, 0, stream>>>(Wg, wgbf);
    k_cvtw<<<cvtblocks, 256, 0, stream>>>(Wu, wubf);
    k_mlp1b<<<NWG1, 512, 0, stream>>>(wgbf, wubf, xbf, ptok, ntiles, tab, hbuf);
    k_cvtw<<<cvtblocks, 256, 0, stream>>>(Wd, wdbf);  // after mlp1: aliases wgbf
    if (fast2) {
      k_mlp2b<0><<<NWG2, 512, 0, stream>>>(wdbf, hbuf, ptok, pw, ntiles, tab, obuf);
      k_reduce<<<N_TOK, 256, 0, stream>>>(obuf, tokrow, out);
    } else {
      k_mlp2b<1><<<NWG2, 512, 0, stream>>>(wdbf, hbuf, ptok, pw, ntiles, tab, out);
    }
  } else {
    dim3 gA(MAX_TILES, I_DIM / FBN, 2);
    dim3 gB(MAX_TILES, H_DIM / FBN, 2);
    k_mlp1<<<gA, 256, 0, stream>>>(Wg, Wu, xbf, ptok, ntiles, tab, hbuf);
    k_mlp2<<<gB, 256, 0, stream>>>(Wd, hbuf, ptok, pw, ntiles, tab, out);
  }
}

// Round 12
// 918.785 us; speedup vs baseline: 1.1999x; 1.1999x over previous
//
#include <hip/hip_runtime.h>
#include <hip/hip_bf16.h>

#define N_TOK 8192
#define H_DIM 1024
#define I_DIM 3584
#define N_EXP 8
#define N_PAIR (N_TOK * 2)

#define BM 256
#define BN 128
#define BK 32
#define MAX_TILES 72   // worst case sum ceil(c_e/256) = 64 + 8 = 72

#define NPAN1 (I_DIM / BN)             // 28
#define NPAN2 (H_DIM / BN)             // 8
#define TG1   4                        // tile-group size (mlp1): 4x512KB A in L2
#define TG2   2                        // tile-group size (mlp2): 2x1.8MB A in L2
#define NWG1  (MAX_TILES * NPAN1)      // 2016 (div by 8)
#define NWG2  (MAX_TILES * NPAN2)      // 576  (div by 8)

typedef short bf16x8 __attribute__((ext_vector_type(8)));
typedef float f32x4 __attribute__((ext_vector_type(4)));

// R8/R10-proven sync discipline: counted vmcnt at entry barrier, lgkmcnt(0)
// before the second barrier, batch STAGE after it, CFENCE around barriers.
#define CFENCE() asm volatile("" ::: "memory")
#define MFMA_BF16 __builtin_amdgcn_mfma_f32_16x16x32_bf16

// ---------------- ws layout (bytes) ----------------
#define WS_CNT      0
#define WS_FILL     64
#define WS_OFF      128
#define WS_NTILES   192
#define WS_TILETAB  256
#define WS_SEL      2048
#define WS_WGT      (WS_SEL    + 2 * N_TOK * 4)
#define WS_PTOK     (WS_WGT    + 2 * N_TOK * 4)
#define WS_PW       (WS_PTOK   + N_PAIR * 4)
#define WS_XBF      (WS_PW     + N_PAIR * 4)
#define WS_HBUF     (WS_XBF    + (size_t)N_TOK * H_DIM * 2)
#define WBF_ELEMS   ((size_t)N_EXP * I_DIM * H_DIM)
#define WS_WGBF     (WS_HBUF + (size_t)N_PAIR * I_DIM * 2)
#define WS_WUBF     (WS_WGBF + WBF_ELEMS * 2)
#define WS_END      (WS_WUBF + WBF_ELEMS * 2)                  // ~252 MB
#define WS_TOKROW   WS_END                                     // 2*N_TOK ints
#define WS_OBUF     (WS_TOKROW + (size_t)2 * N_TOK * 4)
#define WS_END2     (WS_OBUF + (size_t)N_PAIR * H_DIM * 4)     // +67 MB

__device__ __forceinline__ unsigned short f2bf(float f) {
  unsigned int u = __float_as_uint(f);
  unsigned int r = (u + 0x7fffu + ((u >> 16) & 1u)) >> 16;
  return (unsigned short)r;
}

__device__ __forceinline__ uint4 pack8(float4 a, float4 b) {
  uint4 r;
  r.x = (unsigned)f2bf(a.x) | ((unsigned)f2bf(a.y) << 16);
  r.y = (unsigned)f2bf(a.z) | ((unsigned)f2bf(a.w) << 16);
  r.z = (unsigned)f2bf(b.x) | ((unsigned)f2bf(b.y) << 16);
  r.w = (unsigned)f2bf(b.z) | ((unsigned)f2bf(b.w) << 16);
  return r;
}

__device__ __forceinline__ void gll16(const ushort* g, ushort* l) {
  __builtin_amdgcn_global_load_lds(
      (const __attribute__((address_space(1))) unsigned int*)g,
      (__attribute__((address_space(3))) unsigned int*)l, 16, 0, 0);
}

// ---------------- router ----------------
__global__ __launch_bounds__(64) void k_router(
    const float* __restrict__ x, const float* __restrict__ gw,
    float* __restrict__ logits, int* __restrict__ sel,
    float* __restrict__ wgt, int* __restrict__ cnt,
    ushort* __restrict__ xbf)
{
  const int n = blockIdx.x;
  const int lane = threadIdx.x;
  const float4* xr = (const float4*)(x + (size_t)n * H_DIM + lane * 16);
  float4 x0 = xr[0], x1 = xr[1], x2 = xr[2], x3 = xr[3];

  uint4* xo = (uint4*)(xbf + (size_t)n * H_DIM + lane * 16);
  xo[0] = pack8(x0, x1);
  xo[1] = pack8(x2, x3);

  float l[N_EXP];
#pragma unroll
  for (int e = 0; e < N_EXP; ++e) {
    const float4* wr = (const float4*)(gw + e * H_DIM + lane * 16);
    float4 w0 = wr[0], w1 = wr[1], w2 = wr[2], w3 = wr[3];
    float p = x0.x * w0.x + x0.y * w0.y + x0.z * w0.z + x0.w * w0.w
            + x1.x * w1.x + x1.y * w1.y + x1.z * w1.z + x1.w * w1.w
            + x2.x * w2.x + x2.y * w2.y + x2.z * w2.z + x2.w * w2.w
            + x3.x * w3.x + x3.y * w3.y + x3.z * w3.z + x3.w * w3.w;
#pragma unroll
    for (int o = 32; o >= 1; o >>= 1) p += __shfl_xor(p, o, 64);
    l[e] = p;
  }
  float m = l[0];
#pragma unroll
  for (int e = 1; e < N_EXP; ++e) m = fmaxf(m, l[e]);
  float pr[N_EXP]; float den = 0.f;
#pragma unroll
  for (int e = 0; e < N_EXP; ++e) { pr[e] = expf(l[e] - m); den += pr[e]; }
#pragma unroll
  for (int e = 0; e < N_EXP; ++e) pr[e] /= den;
  int i0 = 0; float p0 = pr[0];
#pragma unroll
  for (int e = 1; e < N_EXP; ++e) { if (pr[e] > p0) { p0 = pr[e]; i0 = e; } }
  int i1 = -1; float p1 = -1.f;
#pragma unroll
  for (int e = 0; e < N_EXP; ++e) { if (e != i0 && pr[e] > p1) { p1 = pr[e]; i1 = e; } }
  float rs = 1.f / (p0 + p1);
  if (lane == 0) {
    float* lo = logits + (size_t)n * N_EXP;
#pragma unroll
    for (int e = 0; e < N_EXP; ++e) lo[e] = l[e];
    sel[2 * n] = i0; sel[2 * n + 1] = i1;
    wgt[2 * n] = p0 * rs; wgt[2 * n + 1] = p1 * rs;
    atomicAdd(&cnt[i0], 1);
    atomicAdd(&cnt[i1], 1);
  }
}

// ---------------- prefix sum + tile table ----------------
__global__ void k_prefix(const int* __restrict__ cnt, int* __restrict__ off,
                         int* __restrict__ ntiles, int* __restrict__ tab)
{
  if (threadIdx.x != 0 || blockIdx.x != 0) return;
  int acc = 0, nt = 0;
  for (int e = 0; e < N_EXP; ++e) {
    off[e] = acc;
    int c = cnt[e];
    for (int r = 0; r < c; r += BM) {
      tab[nt * 3 + 0] = e;
      tab[nt * 3 + 1] = acc + r;
      tab[nt * 3 + 2] = (c - r < BM) ? (c - r) : BM;
      nt++;
    }
    acc += c;
  }
  off[N_EXP] = acc;
  *ntiles = nt;
}

// ---------------- scatter (+ token -> pair-row index) ----------------
__global__ __launch_bounds__(256) void k_scatter(
    const int* __restrict__ sel, const float* __restrict__ wgt,
    const int* __restrict__ off, int* __restrict__ fill,
    int* __restrict__ ptok, float* __restrict__ pw,
    int* __restrict__ tokrow)
{
  int n = blockIdx.x * 256 + threadIdx.x;
  if (n >= N_TOK) return;
#pragma unroll
  for (int k = 0; k < 2; ++k) {
    int e = sel[2 * n + k];
    int pos = atomicAdd(&fill[e], 1);
    int row = off[e] + pos;
    ptok[row] = n;
    pw[row] = wgt[2 * n + k];
    if (tokrow) tokrow[2 * n + k] = row;
  }
}

// ---------------- fp32 -> bf16 weight conversion ----------------
__global__ __launch_bounds__(256) void k_cvtw(const float* __restrict__ src,
                                              ushort* __restrict__ dst)
{
  size_t i = (size_t)blockIdx.x * 256 + threadIdx.x;
  const float4* s = (const float4*)(src + i * 8);
  float4 a = s[0], b = s[1];
  ((uint4*)dst)[i] = pack8(a, b);
}

// ---------------- final reduce: out[n] = obuf[r0] + obuf[r1] ----------------
__global__ __launch_bounds__(256) void k_reduce(
    const float* __restrict__ obuf, const int* __restrict__ tokrow,
    float* __restrict__ out)
{
  const int n = blockIdx.x;
  const int t = threadIdx.x;            // 256 threads x float4 = 1024 floats
  const int r0 = tokrow[2 * n];
  const int r1 = tokrow[2 * n + 1];
  const float4* p0 = (const float4*)(obuf + (size_t)r0 * H_DIM);
  const float4* p1 = (const float4*)(obuf + (size_t)r1 * H_DIM);
  float4 a = p0[t], b = p1[t];
  float4 v = make_float4(a.x + b.x, a.y + b.y, a.z + b.z, a.w + b.w);
  ((float4*)(out + (size_t)n * H_DIM))[t] = v;
}

// ================= FAST PATH: R10 structure + tile-group x panel ordering =====

// pass A: h = silu(x@Wg^T) * (x@Wu^T)
__global__ __launch_bounds__(512) void k_mlp1b(
    const ushort* __restrict__ Wg, const ushort* __restrict__ Wu,
    const ushort* __restrict__ xbf, const int* __restrict__ ptok,
    const int* __restrict__ ntiles, const int* __restrict__ tab,
    ushort* __restrict__ hbuf)
{
  __shared__ ushort sA[2][BM * BK];   // 2 x 16 KB
  __shared__ ushort sG[2][BN * BK];   // 2 x 8 KB
  __shared__ ushort sU[2][BN * BK];   // 2 x 8 KB
  __shared__ int stok[BM];

  // XCD chunking, then tile-group x panel ordering: within a group of TG1
  // tiles, iterate panels with tile-inner-fastest so a weight panel is
  // re-read by TG1 consecutive blocks (L2-hot) while the group's A-tiles
  // (TG1 x 512KB) stay L2-resident.
  const int orig = blockIdx.x;
  const int lin = (orig & 7) * (NWG1 >> 3) + (orig >> 3);
  const int grp = lin / (NPAN1 * TG1);
  const int rem = lin % (NPAN1 * TG1);
  const int tile = grp * TG1 + (rem % TG1);
  const int i0 = (rem / TG1) * BN;

  if (tile >= *ntiles) return;
  const int e = tab[tile * 3 + 0];
  const int row0 = tab[tile * 3 + 1];
  const int nrows = tab[tile * 3 + 2];
  const int t = threadIdx.x;

  if (t < BM) {
    int tt = t < nrows ? t : (nrows - 1);
    stok[t] = ptok[row0 + tt];
  }
  __syncthreads();   // drains all prior VMEM -> clean vmcnt baseline

  // T2 pre-swizzled source chunk (R10-verified: bank conflicts = 0)
  const int ak = (((t & 3) ^ ((t >> 3) & 3)) * 8);
  const int ar = t >> 2;
  const ushort* ga0 = xbf + (size_t)stok[ar] * H_DIM + ak;
  const ushort* ga1 = xbf + (size_t)stok[128 + ar] * H_DIM + ak;
  const ushort* gg0 = Wg + (size_t)e * I_DIM * H_DIM + (size_t)(i0 + ar) * H_DIM + ak;
  const ushort* gu0 = Wu + (size_t)e * I_DIM * H_DIM + (size_t)(i0 + ar) * H_DIM + ak;

  const int lane = t & 63, wid = t >> 6;
  const int wm = wid >> 1, wn = wid & 1;   // 4 x 2 wave grid
  const int fr = lane & 15, fq = lane >> 4;
  const int fs = (fq ^ ((fr >> 1) & 3)) * 8;

  f32x4 ag[4][4], au[4][4];
#pragma unroll
  for (int m = 0; m < 4; ++m)
#pragma unroll
    for (int n = 0; n < 4; ++n) { ag[m][n] = (f32x4){0,0,0,0}; au[m][n] = (f32x4){0,0,0,0}; }

#define STAGE1(b, kt) do {                      \
    gll16(ga0 + (kt), &sA[b][t * 8]);           \
    gll16(ga1 + (kt), &sA[b][(512 + t) * 8]);   \
    gll16(gg0 + (kt), &sG[b][t * 8]);           \
    gll16(gu0 + (kt), &sU[b][t * 8]);           \
  } while (0)

#define COMPUTE1(b) do {                                                     \
    bf16x8 a[4], bg[4], bu[4];                                               \
    _Pragma("unroll")                                                        \
    for (int m = 0; m < 4; ++m)                                              \
      a[m] = *(const bf16x8*)(&sA[b][(wm * 64 + m * 16 + fr) * BK + fs]);    \
    _Pragma("unroll")                                                        \
    for (int n = 0; n < 4; ++n) {                                            \
      bg[n] = *(const bf16x8*)(&sG[b][(wn * 64 + n * 16 + fr) * BK + fs]);   \
      bu[n] = *(const bf16x8*)(&sU[b][(wn * 64 + n * 16 + fr) * BK + fs]);   \
    }                                                                        \
    _Pragma("unroll")                                                        \
    for (int m = 0; m < 4; ++m)                                              \
      _Pragma("unroll")                                                      \
      for (int n = 0; n < 4; ++n) {                                          \
        ag[m][n] = MFMA_BF16(a[m], bg[n], ag[m][n], 0, 0, 0);                \
        au[m][n] = MFMA_BF16(a[m], bu[n], au[m][n], 0, 0, 0);                \
      }                                                                      \
  } while (0)

  const int NK = H_DIM / BK;  // 32 (even)
  STAGE1(0, 0);
  CFENCE();                   // pin FIFO: buf0's 4 loads oldest
  STAGE1(1, BK);
#pragma unroll 2
  for (int ki = 0; ki < NK - 2; ++ki) {
    const int cur = ki & 1;
    asm volatile("s_waitcnt vmcnt(4)" ::: "memory");  // buf[cur]'s 4 loads landed
    __builtin_amdgcn_s_barrier();
    CFENCE();
    __builtin_amdgcn_sched_barrier(0);
    COMPUTE1(cur);
    asm volatile("s_waitcnt lgkmcnt(0)" ::: "memory"); // my ds_reads COMPLETE
    __builtin_amdgcn_sched_barrier(0);
    __builtin_amdgcn_s_barrier();                      // everyone's reads complete
    CFENCE();
    STAGE1(cur, (ki + 2) * BK);                        // refill buf[cur]
  }
  asm volatile("s_waitcnt vmcnt(4)" ::: "memory");
  __builtin_amdgcn_s_barrier();
  CFENCE();
  __builtin_amdgcn_sched_barrier(0);
  COMPUTE1(0);                                         // ki = NK-2 (parity 0)
  CFENCE();
  asm volatile("s_waitcnt vmcnt(0) lgkmcnt(0)" ::: "memory");
  __builtin_amdgcn_s_barrier();
  CFENCE();
  __builtin_amdgcn_sched_barrier(0);
  COMPUTE1(1);                                         // ki = NK-1 (parity 1)
#undef STAGE1
#undef COMPUTE1

#pragma unroll
  for (int m = 0; m < 4; ++m) {
    const int rb = wm * 64 + m * 16 + fq * 4;
#pragma unroll
    for (int n = 0; n < 4; ++n) {
      const int col = i0 + wn * 64 + n * 16 + fr;
#pragma unroll
      for (int r = 0; r < 4; ++r) {
        const int row = rb + r;
        if (row < nrows) {
          float g = ag[m][n][r], u = au[m][n][r];
          float hv = (g / (1.f + __expf(-g))) * u;
          hbuf[(size_t)(row0 + row) * I_DIM + col] = f2bf(hv);
        }
      }
    }
  }
}

// pass B: partial = w * (h @ Wd^T); EPI=0 -> plain store to obuf; EPI=1 -> atomicAdd
template <int EPI>
__global__ __launch_bounds__(512) void k_mlp2b(
    const ushort* __restrict__ Wd, const ushort* __restrict__ hbuf,
    const int* __restrict__ ptok, const float* __restrict__ pw,
    const int* __restrict__ ntiles, const int* __restrict__ tab,
    float* __restrict__ dst)
{
  __shared__ ushort sA[2][BM * BK];   // 2 x 16 KB
  __shared__ ushort sB[2][BN * BK];   // 2 x 8 KB
  __shared__ int stok[BM];
  __shared__ float sw[BM];

  const int orig = blockIdx.x;
  const int lin = (orig & 7) * (NWG2 >> 3) + (orig >> 3);
  const int grp = lin / (NPAN2 * TG2);
  const int rem = lin % (NPAN2 * TG2);
  const int tile = grp * TG2 + (rem % TG2);
  const int j0 = (rem / TG2) * BN;

  if (tile >= *ntiles) return;
  const int e = tab[tile * 3 + 0];
  const int row0 = tab[tile * 3 + 1];
  const int nrows = tab[tile * 3 + 2];
  const int t = threadIdx.x;

  if (t < BM) {
    int tt = t < nrows ? t : (nrows - 1);
    stok[t] = ptok[row0 + tt];
    sw[t] = pw[row0 + tt];
  }
  __syncthreads();   // clean vmcnt baseline

  const int ak = (((t & 3) ^ ((t >> 3) & 3)) * 8);
  const int ar = t >> 2;
  int arow0 = row0 + ar;        if (arow0 > N_PAIR - 1) arow0 = N_PAIR - 1;
  int arow1 = row0 + 128 + ar;  if (arow1 > N_PAIR - 1) arow1 = N_PAIR - 1;
  const ushort* ga0 = hbuf + (size_t)arow0 * I_DIM + ak;
  const ushort* ga1 = hbuf + (size_t)arow1 * I_DIM + ak;
  const ushort* gb0 = Wd + (size_t)e * H_DIM * I_DIM + (size_t)(j0 + ar) * I_DIM + ak;

  const int lane = t & 63, wid = t >> 6;
  const int wm = wid >> 1, wn = wid & 1;   // 4 x 2
  const int fr = lane & 15, fq = lane >> 4;
  const int fs = (fq ^ ((fr >> 1) & 3)) * 8;

  f32x4 ac[4][4];
#pragma unroll
  for (int m = 0; m < 4; ++m)
#pragma unroll
    for (int n = 0; n < 4; ++n) ac[m][n] = (f32x4){0,0,0,0};

#define STAGE2(b, kt) do {                      \
    gll16(ga0 + (kt), &sA[b][t * 8]);           \
    gll16(ga1 + (kt), &sA[b][(512 + t) * 8]);   \
    gll16(gb0 + (kt), &sB[b][t * 8]);           \
  } while (0)

#define COMPUTE2(b) do {                                                     \
    bf16x8 a[4], bb[4];                                                      \
    _Pragma("unroll")                                                        \
    for (int m = 0; m < 4; ++m)                                              \
      a[m] = *(const bf16x8*)(&sA[b][(wm * 64 + m * 16 + fr) * BK + fs]);    \
    _Pragma("unroll")                                                        \
    for (int n = 0; n < 4; ++n)                                              \
      bb[n] = *(const bf16x8*)(&sB[b][(wn * 64 + n * 16 + fr) * BK + fs]);   \
    _Pragma("unroll")                                                        \
    for (int m = 0; m < 4; ++m)                                              \
      _Pragma("unroll")                                                      \
      for (int n = 0; n < 4; ++n)                                            \
        ac[m][n] = MFMA_BF16(a[m], bb[n], ac[m][n], 0, 0, 0);                \
  } while (0)

  const int NK = I_DIM / BK;  // 112 (even)
  STAGE2(0, 0);
  CFENCE();
  STAGE2(1, BK);
#pragma unroll 2
  for (int ki = 0; ki < NK - 2; ++ki) {
    const int cur = ki & 1;
    asm volatile("s_waitcnt vmcnt(3)" ::: "memory");  // buf[cur]'s 3 loads landed
    __builtin_amdgcn_s_barrier();
    CFENCE();
    __builtin_amdgcn_sched_barrier(0);
    COMPUTE2(cur);
    asm volatile("s_waitcnt lgkmcnt(0)" ::: "memory");
    __builtin_amdgcn_sched_barrier(0);
    __builtin_amdgcn_s_barrier();
    CFENCE();
    STAGE2(cur, (ki + 2) * BK);
  }
  asm volatile("s_waitcnt vmcnt(3)" ::: "memory");
  __builtin_amdgcn_s_barrier();
  CFENCE();
  __builtin_amdgcn_sched_barrier(0);
  COMPUTE2(0);
  CFENCE();
  asm volatile("s_waitcnt vmcnt(0) lgkmcnt(0)" ::: "memory");
  __builtin_amdgcn_s_barrier();
  CFENCE();
  __builtin_amdgcn_sched_barrier(0);
  COMPUTE2(1);
#undef STAGE2
#undef COMPUTE2

#pragma unroll
  for (int m = 0; m < 4; ++m) {
    const int rb = wm * 64 + m * 16 + fq * 4;
#pragma unroll
    for (int n = 0; n < 4; ++n) {
      const int col = j0 + wn * 64 + n * 16 + fr;
#pragma unroll
      for (int r = 0; r < 4; ++r) {
        const int row = rb + r;
        if (row < nrows) {
          float v = ac[m][n][r] * sw[row];
          if (EPI == 0) {
            dst[(size_t)(row0 + row) * H_DIM + col] = v;          // obuf, no atomics
          } else {
            atomicAdd(&dst[(size_t)stok[row] * H_DIM + col], v);  // out
          }
        }
      }
    }
  }
}

// ================= FALLBACK PATH (fp32 weights, reg-staged, 128-tile) =====

#define FBM 128
#define FBN 128

__global__ __launch_bounds__(256) void k_mlp1(
    const float* __restrict__ Wg, const float* __restrict__ Wu,
    const ushort* __restrict__ xbf, const int* __restrict__ ptok,
    const int* __restrict__ ntiles, const int* __restrict__ tab,
    ushort* __restrict__ hbuf)
{
  __shared__ ushort sA[FBM * BK];
  __shared__ ushort sG[FBN * BK];
  __shared__ ushort sU[FBN * BK];
  __shared__ int stok[FBM];

  const int tile = blockIdx.x;
  if (tile >= *ntiles) return;
  const int e = tab[tile * 3 + 0];
  const int row0 = tab[tile * 3 + 1] + (blockIdx.z ? FBM : 0);
  int nrows = tab[tile * 3 + 2] - (blockIdx.z ? FBM : 0);
  if (nrows <= 0) return;
  if (nrows > FBM) nrows = FBM;
  const int i0 = blockIdx.y * FBN;
  const int t = threadIdx.x;

  if (t < FBM) {
    int tt = t < nrows ? t : (nrows - 1);
    stok[t] = ptok[row0 + tt];
  }
  __syncthreads();

  const int ak = (t & 3) * 8;
  const ushort* ga0 = xbf + (size_t)stok[t >> 2] * H_DIM + ak;
  const ushort* ga1 = xbf + (size_t)stok[64 + (t >> 2)] * H_DIM + ak;
  ushort* la0 = sA + (size_t)t * 8;
  ushort* la1 = sA + (size_t)(256 + t) * 8;

  const int wr = t >> 1, wcb = (t & 1) * 16;
  const float* gwg = Wg + (size_t)e * I_DIM * H_DIM + (size_t)(i0 + wr) * H_DIM + wcb;
  const float* gwu = Wu + (size_t)e * I_DIM * H_DIM + (size_t)(i0 + wr) * H_DIM + wcb;
  ushort* lwg = sG + wr * BK + wcb;
  ushort* lwu = sU + wr * BK + wcb;

  const int lane = t & 63, wid = t >> 6;
  const int wm = wid >> 1, wn = wid & 1;
  const int fr = lane & 15, fq = lane >> 4;

  f32x4 ag[4][4], au[4][4];
#pragma unroll
  for (int m = 0; m < 4; ++m)
#pragma unroll
    for (int n = 0; n < 4; ++n) { ag[m][n] = (f32x4){0,0,0,0}; au[m][n] = (f32x4){0,0,0,0}; }

  for (int kt = 0; kt < H_DIM; kt += BK) {
    gll16(ga0 + kt, la0);
    gll16(ga1 + kt, la1);

    const float4* pg = (const float4*)(gwg + kt);
    const float4* pu = (const float4*)(gwu + kt);
    float4 g0 = pg[0], g1 = pg[1], g2 = pg[2], g3 = pg[3];
    float4 u0 = pu[0], u1 = pu[1], u2 = pu[2], u3 = pu[3];
    ((uint4*)lwg)[0] = pack8(g0, g1);
    ((uint4*)lwg)[1] = pack8(g2, g3);
    ((uint4*)lwu)[0] = pack8(u0, u1);
    ((uint4*)lwu)[1] = pack8(u2, u3);
    __syncthreads();

    bf16x8 a[4], bg[4], bu[4];
#pragma unroll
    for (int m = 0; m < 4; ++m)
      a[m] = *(const bf16x8*)(sA + (wm * 64 + m * 16 + fr) * BK + fq * 8);
#pragma unroll
    for (int n = 0; n < 4; ++n) {
      bg[n] = *(const bf16x8*)(sG + (wn * 64 + n * 16 + fr) * BK + fq * 8);
      bu[n] = *(const bf16x8*)(sU + (wn * 64 + n * 16 + fr) * BK + fq * 8);
    }
#pragma unroll
    for (int m = 0; m < 4; ++m)
#pragma unroll
      for (int n = 0; n < 4; ++n) {
        ag[m][n] = MFMA_BF16(a[m], bg[n], ag[m][n], 0, 0, 0);
        au[m][n] = MFMA_BF16(a[m], bu[n], au[m][n], 0, 0, 0);
      }
    __syncthreads();
  }

#pragma unroll
  for (int m = 0; m < 4; ++m) {
    const int rb = wm * 64 + m * 16 + fq * 4;
#pragma unroll
    for (int n = 0; n < 4; ++n) {
      const int col = i0 + wn * 64 + n * 16 + fr;
#pragma unroll
      for (int r = 0; r < 4; ++r) {
        const int row = rb + r;
        if (row < nrows) {
          float g = ag[m][n][r], u = au[m][n][r];
          float hv = (g / (1.f + __expf(-g))) * u;
          hbuf[(size_t)(row0 + row) * I_DIM + col] = f2bf(hv);
        }
      }
    }
  }
}

__global__ __launch_bounds__(256) void k_mlp2(
    const float* __restrict__ Wd, const ushort* __restrict__ hbuf,
    const int* __restrict__ ptok, const float* __restrict__ pw,
    const int* __restrict__ ntiles, const int* __restrict__ tab,
    float* __restrict__ out)
{
  __shared__ ushort sA[FBM * BK];
  __shared__ ushort sB[FBN * BK];
  __shared__ int stok[FBM];
  __shared__ float sw[FBM];

  const int tile = blockIdx.x;
  if (tile >= *ntiles) return;
  const int e = tab[tile * 3 + 0];
  const int row0 = tab[tile * 3 + 1] + (blockIdx.z ? FBM : 0);
  int nrows = tab[tile * 3 + 2] - (blockIdx.z ? FBM : 0);
  if (nrows <= 0) return;
  if (nrows > FBM) nrows = FBM;
  const int j0 = blockIdx.y * FBN;
  const int t = threadIdx.x;

  if (t < FBM) {
    int tt = t < nrows ? t : (nrows - 1);
    stok[t] = ptok[row0 + tt];
    sw[t] = pw[row0 + tt];
  }
  __syncthreads();

  const int ak = (t & 3) * 8;
  int arow0 = row0 + (t >> 2);       if (arow0 > N_PAIR - 1) arow0 = N_PAIR - 1;
  int arow1 = row0 + 64 + (t >> 2);  if (arow1 > N_PAIR - 1) arow1 = N_PAIR - 1;
  const ushort* ga0 = hbuf + (size_t)arow0 * I_DIM + ak;
  const ushort* ga1 = hbuf + (size_t)arow1 * I_DIM + ak;
  ushort* la0 = sA + (size_t)t * 8;
  ushort* la1 = sA + (size_t)(256 + t) * 8;

  const int wr = t >> 1, wcb = (t & 1) * 16;
  const float* gb = Wd + (size_t)e * H_DIM * I_DIM + (size_t)(j0 + wr) * I_DIM + wcb;
  ushort* lb = sB + wr * BK + wcb;

  const int lane = t & 63, wid = t >> 6;
  const int wm = wid >> 1, wn = wid & 1;
  const int fr = lane & 15, fq = lane >> 4;

  f32x4 ac[4][4];
#pragma unroll
  for (int m = 0; m < 4; ++m)
#pragma unroll
    for (int n = 0; n < 4; ++n) ac[m][n] = (f32x4){0,0,0,0};

  for (int kt = 0; kt < I_DIM; kt += BK) {
    gll16(ga0 + kt, la0);
    gll16(ga1 + kt, la1);

    const float4* pb = (const float4*)(gb + kt);
    float4 b0 = pb[0], b1 = pb[1], b2 = pb[2], b3 = pb[3];
    ((uint4*)lb)[0] = pack8(b0, b1);
    ((uint4*)lb)[1] = pack8(b2, b3);
    __syncthreads();

    bf16x8 a[4], bb[4];
#pragma unroll
    for (int m = 0; m < 4; ++m)
      a[m] = *(const bf16x8*)(sA + (wm * 64 + m * 16 + fr) * BK + fq * 8);
#pragma unroll
    for (int n = 0; n < 4; ++n)
      bb[n] = *(const bf16x8*)(sB + (wn * 64 + n * 16 + fr) * BK + fq * 8);
#pragma unroll
    for (int m = 0; m < 4; ++m)
#pragma unroll
      for (int n = 0; n < 4; ++n)
        ac[m][n] = MFMA_BF16(a[m], bb[n], ac[m][n], 0, 0, 0);
    __syncthreads();
  }

#pragma unroll
  for (int m = 0; m < 4; ++m) {
    const int rb = wm * 64 + m * 16 + fq * 4;
#pragma unroll
    for (int n = 0; n < 4; ++n) {
      const int col = j0 + wn * 64 + n * 16 + fr;
#pragma unroll
      for (int r = 0; r < 4; ++r) {
        const int row = rb + r;
        if (row < nrows) {
          float v = ac[m][n][r] * sw[row];
          atomicAdd(&out[(size_t)stok[row] * H_DIM + col], v);
        }
      }
    }
  }
}

// ---------------- host ----------------
extern "C" void kernel_launch(void* const* d_in, const int* in_sizes, int n_in,
                              void* d_out, int out_size, void* d_ws, size_t ws_size,
                              hipStream_t stream)
{
  const float* x  = (const float*)d_in[0];
  const float* gw = (const float*)d_in[1];
  const float* Wg = (const float*)d_in[2];
  const float* Wu = (const float*)d_in[3];
  const float* Wd = (const float*)d_in[4];

  float* out    = (float*)d_out;
  float* logits = out + (size_t)N_TOK * H_DIM;

  char* ws = (char*)d_ws;
  int*    cnt    = (int*)(ws + WS_CNT);
  int*    fill   = (int*)(ws + WS_FILL);
  int*    off    = (int*)(ws + WS_OFF);
  int*    ntiles = (int*)(ws + WS_NTILES);
  int*    tab    = (int*)(ws + WS_TILETAB);
  int*    sel    = (int*)(ws + WS_SEL);
  float*  wgt    = (float*)(ws + WS_WGT);
  int*    ptok   = (int*)(ws + WS_PTOK);
  float*  pw     = (float*)(ws + WS_PW);
  ushort* xbf    = (ushort*)(ws + WS_XBF);
  ushort* hbuf   = (ushort*)(ws + WS_HBUF);
  ushort* wgbf   = (ushort*)(ws + WS_WGBF);
  ushort* wubf   = (ushort*)(ws + WS_WUBF);
  ushort* wdbf   = wgbf;  // aliases Wg slot (disjoint live ranges)
  int*    tokrow = (int*)(ws + WS_TOKROW);
  float*  obuf   = (float*)(ws + WS_OBUF);

  const bool fast  = (ws_size >= WS_END);
  const bool fast2 = (ws_size >= WS_END2);   // room for obuf + tokrow

  if (!(fast && fast2))
    hipMemsetAsync(d_out, 0, (size_t)N_TOK * H_DIM * sizeof(float), stream);
  hipMemsetAsync(ws, 0, 128, stream);  // cnt + fill

  k_router<<<N_TOK, 64, 0, stream>>>(x, gw, logits, sel, wgt, cnt, xbf);
  k_prefix<<<1, 64, 0, stream>>>(cnt, off, ntiles, tab);
  k_scatter<<<N_TOK / 256, 256, 0, stream>>>(sel, wgt, off, fill, ptok, pw,
                                             fast2 ? tokrow : (int*)nullptr);

  const int cvtblocks = (int)(WBF_ELEMS / 8 / 256);  // 14336

  if (fast) {
    k_cvtw<<<cvtblocks, 256, 0, stream>>>(Wg, wgbf);
    k_cvtw<<<cvtblocks, 256, 0, stream>>>(Wu, wubf);
    k_mlp1b<<<NWG1, 512, 0, stream>>>(wgbf, wubf, xbf, ptok, ntiles, tab, hbuf);
    k_cvtw<<<cvtblocks, 256, 0, stream>>>(Wd, wdbf);  // after mlp1: aliases wgbf
    if (fast2) {
      k_mlp2b<0><<<NWG2, 512, 0, stream>>>(wdbf, hbuf, ptok, pw, ntiles, tab, obuf);
      k_reduce<<<N_TOK, 256, 0, stream>>>(obuf, tokrow, out);
    } else {
      k_mlp2b<1><<<NWG2, 512, 0, stream>>>(wdbf, hbuf, ptok, pw, ntiles, tab, out);
    }
  } else {
    dim3 gA(MAX_TILES, I_DIM / FBN, 2);
    dim3 gB(MAX_TILES, H_DIM / FBN, 2);
    k_mlp1<<<gA, 256, 0, stream>>>(Wg, Wu, xbf, ptok, ntiles, tab, hbuf);
    k_mlp2<<<gB, 256, 0, stream>>>(Wd, hbuf, ptok, pw, ntiles, tab, out);
  }
}